// Round 5
// baseline (1046.981 us; speedup 1.0000x reference)
//
#include <hip/hip_runtime.h>
#include <hip/hip_bf16.h>

// ---------------------------------------------------------------------------
// ScaledDotProductAttentionMemory, round 4:
//  - exp/pv grids restored to full wave capacity (16 q per wave, 2048 blocks)
//  - projection GEMMs: m97 recipe — bf16 A (pre-converted) + B staged via
//    global_load_lds width=16 into linear LDS, 2-barrier double-buffered loop
// Outputs: out (8,1024,1024) fp32 ; att (8,16,1024,1064) fp32
// ---------------------------------------------------------------------------

#define B_ 8
#define NQ 1024
#define NK 1024
#define DM 1024
#define H_ 16
#define DK 64
#define NKM 1064   // nk + M
#define NKP 1104   // padded row length for Kh/Vt

typedef __attribute__((ext_vector_type(8))) short bf16x8;
typedef __attribute__((ext_vector_type(4))) float f32x4;
typedef __attribute__((ext_vector_type(4))) short short4v;

static __device__ __forceinline__ short f2bf(float x) {
    __hip_bfloat16 h = __float2bfloat16(x);
    return __builtin_bit_cast(short, h);
}
static __device__ __forceinline__ float bf2f(short s) {
    unsigned int u = ((unsigned int)(unsigned short)s) << 16;
    return __builtin_bit_cast(float, u);
}

static __device__ __forceinline__ bf16x8 pack8(const float* __restrict__ p) {
    float4 f0 = *(const float4*)p;
    float4 f1 = *(const float4*)(p + 4);
    bf16x8 a;
    a[0] = f2bf(f0.x); a[1] = f2bf(f0.y); a[2] = f2bf(f0.z); a[3] = f2bf(f0.w);
    a[4] = f2bf(f1.x); a[5] = f2bf(f1.y); a[6] = f2bf(f1.z); a[7] = f2bf(f1.w);
    return a;
}

// async global->LDS, 16B per lane; LDS dest is wave-uniform base + lane*16
static __device__ __forceinline__ void gload16(const short* g, short* l) {
    __builtin_amdgcn_global_load_lds(
        (__attribute__((address_space(1))) void*)const_cast<short*>(g),
        (__attribute__((address_space(3))) void*)l, 16, 0, 0);
}

// --- mask dtype probe: bool(1B) vs int32(4B) -------------------------------
__global__ void detect_mask_kernel(const unsigned int* __restrict__ m, int n_dwords,
                                   int* __restrict__ flag) {
    __shared__ int any_big;
    if (threadIdx.x == 0) any_big = 0;
    __syncthreads();
    for (int i = threadIdx.x; i < n_dwords; i += blockDim.x)
        if (m[i] > 1u) any_big = 1;
    __syncthreads();
    if (threadIdx.x == 0) *flag = any_big ? 0 : 1;   // 1 => int32, 0 => bytes
}

// --- W (K x N) fp32 -> WT (N x K) bf16 --------------------------------------
__global__ void transpose_w_kernel(const float* __restrict__ W, short* __restrict__ WT) {
    __shared__ float t[32][33];
    int tx = threadIdx.x & 31, ty = threadIdx.x >> 5;
    int k0 = blockIdx.x * 32, n0 = blockIdx.y * 32;
#pragma unroll
    for (int r = 0; r < 4; r++)
        t[ty + 8 * r][tx] = W[(size_t)(k0 + ty + 8 * r) * DM + n0 + tx];
    __syncthreads();
#pragma unroll
    for (int r = 0; r < 4; r++)
        WT[(size_t)(n0 + ty + 8 * r) * DM + k0 + tx] = f2bf(t[tx][ty + 8 * r]);
}

// --- fp32 -> bf16 convert of the 3 input tensors (contiguous dest) ----------
__global__ void convert_bf16_kernel(const float* __restrict__ a, const float* __restrict__ b,
                                    const float* __restrict__ c, short* __restrict__ out) {
    const size_t NT = (size_t)B_ * NQ * DM;          // 8388608 per tensor
    const size_t total = NT * 3;
    size_t i = ((size_t)blockIdx.x * 256 + threadIdx.x) * 8;
    const size_t step = (size_t)gridDim.x * 256 * 8;
    for (; i < total; i += step) {
        const float* src = (i < NT) ? (a + i) : (i < 2 * NT) ? (b + (i - NT)) : (c + (i - 2 * NT));
        *(bf16x8*)(out + i) = pack8(src);
    }
}

// --- memory-slot rows of Kh / Vt (rows 1024..1103; zeros past 1063) --------
__global__ void fill_mem_kernel(const float* __restrict__ m_k, const float* __restrict__ m_v,
                                short* __restrict__ Kh, short* __restrict__ Vt) {
    int blk = blockIdx.x;           // 128 bh * 20 row-groups
    int bh = blk / 20, rb = blk % 20;
    int r = rb * 4 + (threadIdx.x >> 6);    // 0..79
    int d = threadIdx.x & 63;
    int h = bh & 15;
    float kv = 0.f, vv = 0.f;
    if (r < 40) {
        kv = 8.0f * m_k[(size_t)(r * H_ + h) * DK + d];               // sqrt(DK)=8
        vv = 6.324555320336759f * m_v[(size_t)(r * H_ + h) * DK + d]; // sqrt(M)
    }
    int kk = 1024 + r;
    Kh[((size_t)bh * NKP + kk) * 64 + d] = f2bf(kv);
    Vt[((size_t)bh * 64 + d) * NKP + kk] = f2bf(vv);
}

// ---------------------------------------------------------------------------
// m97-style GEMM: C[8192x1024] = A(bf16) @ BT^T + bias.
// 128x128 tile, BK=32, linear LDS, global_load_lds x16, 2-barrier dbuf.
// MODE 0: -> Qh[bh][q][64]   MODE 1: -> Kh[bh][kk][64]
// MODE 2: -> Vt[bh][d][kk]   MODE 3: -> outF fp32
// ---------------------------------------------------------------------------
template <int MODE>
__global__ __launch_bounds__(256) void gemm_tile_kernel(
    const short* __restrict__ Ab, const short* __restrict__ BT,
    const float* __restrict__ bias,
    float* __restrict__ outF, short* __restrict__ outB) {
    __shared__ short As[2][4096];   // [128][32] linear
    __shared__ short Bs[2][4096];

    const int tid = threadIdx.x;
    const int lane = tid & 63;
    const int wid = tid >> 6;
    int swz = (blockIdx.x & 7) * 64 + (blockIdx.x >> 3);
    const int mt = swz >> 3, nt = swz & 7;
    const int brow = mt * 128, bcol = nt * 128;
    const int wr = wid >> 1, wc = wid & 1;
    const int l15 = lane & 15, lg = lane >> 4;

    f32x4 acc[4][4];
#pragma unroll
    for (int m = 0; m < 4; m++)
#pragma unroll
        for (int n = 0; n < 4; n++) acc[m][n] = f32x4{0.f, 0.f, 0.f, 0.f};

    auto stage = [&](int buf, int k0) {
#pragma unroll
        for (int i = 0; i < 2; i++) {
            int c = tid + i * 256;               // 16B chunk id, 0..511
            int row = c >> 2, slot = c & 3;
            int base = (c & ~63) * 8;            // wave-uniform LDS short offset
            gload16(Ab + (size_t)(brow + row) * DM + k0 + slot * 8, &As[buf][base]);
            gload16(BT + (size_t)(bcol + row) * DM + k0 + slot * 8, &Bs[buf][base]);
        }
    };

    stage(0, 0);
    for (int kt = 0; kt < 32; ++kt) {
        __syncthreads();                         // drains gload of buf[kt&1]
        if (kt + 1 < 32) stage((kt + 1) & 1, (kt + 1) * 32);
        const short* Ab_ = As[kt & 1];
        const short* Bb_ = Bs[kt & 1];
        bf16x8 a[4], b[4];
#pragma unroll
        for (int m = 0; m < 4; m++)
            a[m] = *(const bf16x8*)(Ab_ + (wr * 64 + m * 16 + l15) * 32 + lg * 8);
#pragma unroll
        for (int n = 0; n < 4; n++)
            b[n] = *(const bf16x8*)(Bb_ + (wc * 64 + n * 16 + l15) * 32 + lg * 8);
#pragma unroll
        for (int m = 0; m < 4; m++)
#pragma unroll
            for (int n = 0; n < 4; n++)
                acc[m][n] = __builtin_amdgcn_mfma_f32_16x16x32_bf16(a[m], b[n], acc[m][n], 0, 0, 0);
    }

#pragma unroll
    for (int n = 0; n < 4; n++) {
        int col = bcol + wc * 64 + n * 16 + l15;
        float bval = bias[col];
#pragma unroll
        for (int m = 0; m < 4; m++) {
            int row0 = brow + wr * 64 + m * 16 + lg * 4;
            if (MODE == 3) {
#pragma unroll
                for (int r = 0; r < 4; r++)
                    outF[(size_t)(row0 + r) * DM + col] = acc[m][n][r] + bval;
            } else if (MODE == 0) {
                int h = col >> 6, d = col & 63;
#pragma unroll
                for (int r = 0; r < 4; r++) {
                    int row = row0 + r;
                    int b = row >> 10, q = row & 1023;
                    outB[((size_t)(b * H_ + h) * NQ + q) * 64 + d] = f2bf(acc[m][n][r] + bval);
                }
            } else if (MODE == 1) {
                int h = col >> 6, d = col & 63;
#pragma unroll
                for (int r = 0; r < 4; r++) {
                    int row = row0 + r;
                    int b = row >> 10, kk = row & 1023;
                    outB[((size_t)(b * H_ + h) * NKP + kk) * 64 + d] = f2bf(acc[m][n][r] + bval);
                }
            } else {  // MODE 2: Vt[bh][d][kk]
                int h = col >> 6, d = col & 63;
                int b = row0 >> 10, kk0 = row0 & 1023;
                short4v sv;
#pragma unroll
                for (int r = 0; r < 4; r++) sv[r] = f2bf(acc[m][n][r] + bval);
                *(short4v*)(outB + ((size_t)(b * H_ + h) * 64 + d) * NKP + kk0) = sv;
            }
        }
    }
}

// ---------------------------------------------------------------------------
// Pass 1: swapped-operand QK^T -> exp -> unnormalized P + rowsum inv.
// One wave = 16 q rows x full 1088 kk strip. 2048 blocks x 4 waves.
// Per-lane fragment: q = lane&15, kk = base + (lane>>4)*4 + r.
// ---------------------------------------------------------------------------
template <int PF>
__global__ __launch_bounds__(256) void exp_kernel(
    const short* __restrict__ Qh, const short* __restrict__ Kh,
    const unsigned char* __restrict__ mb, const int* __restrict__ mi,
    const int* __restrict__ flag,
    short* __restrict__ P, float* __restrict__ attF, float* __restrict__ invv) {
    int swz = (blockIdx.x & 7) * 256 + (blockIdx.x >> 3);   // 2048 blocks
    int bh = swz >> 4;                                      // 16 blocks per bh
    int wid = threadIdx.x >> 6;
    int q0 = (swz & 15) * 64 + wid * 16;
    int lane = threadIdx.x & 63;
    int l15 = lane & 15, lg = lane >> 4;

    const short* Qb = Qh + (size_t)bh * NQ * 64;
    const short* Kb = Kh + (size_t)bh * NKP * 64;
    const int is32 = *flag;

    bf16x8 aq0 = *(const bf16x8*)(Qb + (size_t)(q0 + l15) * 64 + lg * 8);
    bf16x8 aq1 = *(const bf16x8*)(Qb + (size_t)(q0 + l15) * 64 + 32 + lg * 8);

    float rs = 0.f;
    size_t qrow = (size_t)bh * NQ + q0 + l15;

    for (int c = 0; c < 34; ++c) {
        int ntl = (c == 33) ? 1 : 2;      // kk >= 1072 entirely dead
        for (int tl = 0; tl < ntl; ++tl) {
            int kt = c * 32 + tl * 16;
            const short* Kr = Kb + (size_t)(kt + l15) * 64;
            bf16x8 k0 = *(const bf16x8*)(Kr + lg * 8);
            bf16x8 k1 = *(const bf16x8*)(Kr + 32 + lg * 8);
            f32x4 s = {0.f, 0.f, 0.f, 0.f};
            s = __builtin_amdgcn_mfma_f32_16x16x32_bf16(k0, aq0, s, 0, 0, 0);
            s = __builtin_amdgcn_mfma_f32_16x16x32_bf16(k1, aq1, s, 0, 0, 0);
            int kkbase = kt + lg * 4;
            unsigned mu = 0;
            if (kkbase < NK) {
                if (is32) {
                    int4 mv = *(const int4*)(mi + qrow * NK + kkbase);
                    mu = (mv.x ? 1u : 0u) | (mv.y ? 0x100u : 0u) |
                         (mv.z ? 0x10000u : 0u) | (mv.w ? 0x1000000u : 0u);
                } else {
                    mu = *(const unsigned*)(mb + qrow * NK + kkbase);
                }
            }
            float e[4];
#pragma unroll
            for (int r = 0; r < 4; r++) {
                bool dead = (kkbase + r >= NKM) || (((mu >> (8 * r)) & 0xffu) != 0u);
                float ev = __expf(s[r] * 0.125f);
                e[r] = dead ? 0.f : ev;
                rs += e[r];
            }
            if (kkbase < NKM) {
                if (PF == 0) {
                    short4v pv;
                    pv[0] = f2bf(e[0]); pv[1] = f2bf(e[1]);
                    pv[2] = f2bf(e[2]); pv[3] = f2bf(e[3]);
                    *(short4v*)(P + qrow * NKM + kkbase) = pv;
                } else {
                    float4 fv = {e[0], e[1], e[2], e[3]};
                    *(float4*)(attF + qrow * NKM + kkbase) = fv;
                }
            }
        }
    }
    rs += __shfl_xor(rs, 16);
    rs += __shfl_xor(rs, 32);
    if (lg == 0) invv[qrow] = 1.f / rs;
}

// ---------------------------------------------------------------------------
// Pass 2: att = P*inv (coalesced) + PV MFMA -> Ow = (P@V)*inv bf16.
// One wave = 16 q x full strip. 2048 blocks x 4 waves.
// ---------------------------------------------------------------------------
template <int PF>
__global__ __launch_bounds__(256) void pv_norm_kernel(
    const short* __restrict__ P, const short* __restrict__ Vt,
    const float* __restrict__ invv,
    float* __restrict__ att, short* __restrict__ Ow) {
    int swz = (blockIdx.x & 7) * 256 + (blockIdx.x >> 3);
    int bh = swz >> 4;
    int wid = threadIdx.x >> 6;
    int q0 = (swz & 15) * 64 + wid * 16;
    int lane = threadIdx.x & 63;
    int l15 = lane & 15, lg = lane >> 4;

    const short* Vb = Vt + (size_t)bh * 64 * NKP;
    size_t qrow = (size_t)bh * NQ + q0 + l15;
    float invq = invv[qrow];

    f32x4 po[4];
#pragma unroll
    for (int dt = 0; dt < 4; dt++) po[dt] = f32x4{0.f, 0.f, 0.f, 0.f};

    for (int c = 0; c < 34; ++c) {
        int kks = c * 32 + lg * 8;
        bf16x8 bv[4];
#pragma unroll
        for (int dt = 0; dt < 4; dt++)
            bv[dt] = *(const bf16x8*)(Vb + (size_t)(dt * 16 + l15) * NKP + kks);
        bf16x8 a;
        if (PF == 0) {
            a = *(const bf16x8*)(P + qrow * NKM + kks);   // tail overread * V==0
            if (kks < NKM) {
                float4 w0, w1;
                w0.x = bf2f(a[0]) * invq; w0.y = bf2f(a[1]) * invq;
                w0.z = bf2f(a[2]) * invq; w0.w = bf2f(a[3]) * invq;
                w1.x = bf2f(a[4]) * invq; w1.y = bf2f(a[5]) * invq;
                w1.z = bf2f(a[6]) * invq; w1.w = bf2f(a[7]) * invq;
                *(float4*)(att + qrow * NKM + kks) = w0;
                *(float4*)(att + qrow * NKM + kks + 4) = w1;
            }
        } else {
            if (kks < NKM) {
                float4 f0 = *(const float4*)(att + qrow * NKM + kks);
                float4 f1 = *(const float4*)(att + qrow * NKM + kks + 4);
                a[0] = f2bf(f0.x); a[1] = f2bf(f0.y); a[2] = f2bf(f0.z); a[3] = f2bf(f0.w);
                a[4] = f2bf(f1.x); a[5] = f2bf(f1.y); a[6] = f2bf(f1.z); a[7] = f2bf(f1.w);
                float4 w0, w1;
                w0.x = f0.x * invq; w0.y = f0.y * invq; w0.z = f0.z * invq; w0.w = f0.w * invq;
                w1.x = f1.x * invq; w1.y = f1.y * invq; w1.z = f1.z * invq; w1.w = f1.w * invq;
                *(float4*)(att + qrow * NKM + kks) = w0;
                *(float4*)(att + qrow * NKM + kks + 4) = w1;
            } else {
                a = bf16x8{0, 0, 0, 0, 0, 0, 0, 0};
            }
        }
#pragma unroll
        for (int dt = 0; dt < 4; dt++)
            po[dt] = __builtin_amdgcn_mfma_f32_16x16x32_bf16(a, bv[dt], po[dt], 0, 0, 0);
    }

    float invr[4];
#pragma unroll
    for (int r = 0; r < 4; r++)
        invr[r] = invv[(size_t)bh * NQ + q0 + lg * 4 + r];
    int b = bh >> 4, h = bh & 15;
#pragma unroll
    for (int dt = 0; dt < 4; dt++)
#pragma unroll
        for (int r = 0; r < 4; r++)
            Ow[((size_t)b * NQ + q0 + lg * 4 + r) * DM + h * 64 + dt * 16 + l15] =
                f2bf(po[dt][r] * invr[r]);
}

extern "C" void kernel_launch(void* const* d_in, const int* in_sizes, int n_in,
                              void* d_out, int out_size, void* d_ws, size_t ws_size,
                              hipStream_t stream) {
    const float* queries = (const float*)d_in[0];
    const float* keys    = (const float*)d_in[1];
    const float* values  = (const float*)d_in[2];
    const void*  mask    = d_in[3];
    const float* Wq = (const float*)d_in[4];
    const float* bq = (const float*)d_in[5];
    const float* Wk = (const float*)d_in[6];
    const float* bk = (const float*)d_in[7];
    const float* Wv = (const float*)d_in[8];
    const float* bv = (const float*)d_in[9];
    const float* Wo = (const float*)d_in[10];
    const float* bo = (const float*)d_in[11];
    const float* m_k = (const float*)d_in[12];
    const float* m_v = (const float*)d_in[13];

    // workspace layout
    short* WqT = (short*)d_ws;
    short* WkT = WqT + (size_t)DM * DM;
    short* WvT = WkT + (size_t)DM * DM;
    short* WoT = WvT + (size_t)DM * DM;
    short* Qh  = WoT + (size_t)DM * DM;                 // [128][1024][64]
    short* Kh  = Qh + (size_t)B_ * H_ * NQ * DK;        // [128][1104][64]
    short* Vt  = Kh + (size_t)B_ * H_ * NKP * DK;       // [128][64][1104]
    short* Ow  = Vt + (size_t)B_ * H_ * DK * NKP;       // [8192][1024]
    char*  after = (char*)(Ow + (size_t)B_ * NQ * DM);
    int*   flag = (int*)after;
    float* invv = (float*)(after + 64);                 // [128][1024]
    short* P    = (short*)(after + 64 + (size_t)B_ * H_ * NQ * 4);  // [128][1024][1064]
    size_t need = ((char*)P - (char*)d_ws) + ((size_t)B_ * H_ * NQ * NKM + 128) * 2;
    const bool usep = (ws_size >= need);
    // bf16 copies of q/k/v inputs, aliased onto P (dead once exp_kernel runs)
    short* Qbf = P;
    short* Kbf = Qbf + (size_t)B_ * NQ * DM;
    short* Vbf = Kbf + (size_t)B_ * NQ * DM;

    float* outO = (float*)d_out;                         // 8*1024*1024
    float* att  = outO + (size_t)B_ * NQ * DM;           // 8*16*1024*1064

    detect_mask_kernel<<<1, 256, 0, stream>>>((const unsigned int*)mask, 4096, flag);

    dim3 tg(32, 32);
    transpose_w_kernel<<<tg, 256, 0, stream>>>(Wq, WqT);
    transpose_w_kernel<<<tg, 256, 0, stream>>>(Wk, WkT);
    transpose_w_kernel<<<tg, 256, 0, stream>>>(Wv, WvT);
    transpose_w_kernel<<<tg, 256, 0, stream>>>(Wo, WoT);

    convert_bf16_kernel<<<4096, 256, 0, stream>>>(queries, keys, values, Qbf);

    gemm_tile_kernel<0><<<512, 256, 0, stream>>>(Qbf, WqT, bq, nullptr, Qh);
    gemm_tile_kernel<1><<<512, 256, 0, stream>>>(Kbf, WkT, bk, nullptr, Kh);
    gemm_tile_kernel<2><<<512, 256, 0, stream>>>(Vbf, WvT, bv, nullptr, Vt);

    fill_mem_kernel<<<2560, 256, 0, stream>>>(m_k, m_v, Kh, Vt);

    if (usep) {
        exp_kernel<0><<<2048, 256, 0, stream>>>(Qh, Kh, (const unsigned char*)mask,
                                                (const int*)mask, flag, P, att, invv);
        pv_norm_kernel<0><<<2048, 256, 0, stream>>>(P, Vt, invv, att, Ow);
    } else {
        exp_kernel<1><<<2048, 256, 0, stream>>>(Qh, Kh, (const unsigned char*)mask,
                                                (const int*)mask, flag, nullptr, att, invv);
        pv_norm_kernel<1><<<2048, 256, 0, stream>>>(nullptr, Vt, invv, att, Ow);
    }

    gemm_tile_kernel<3><<<512, 256, 0, stream>>>(Ow, WoT, bo, outO, nullptr);
}

// Round 6
// 697.611 us; speedup vs baseline: 1.5008x; 1.5008x over previous
//
#include <hip/hip_runtime.h>
#include <hip/hip_bf16.h>

// ---------------------------------------------------------------------------
// ScaledDotProductAttentionMemory, round 5:
//  - exp+PV FUSED: unnormalized bf16 P lives in wave-private LDS (never HBM).
//    Kills round-4/5's 279 MB P write + 279 MB P read + RFO stalls from
//    2128 B (non-64B-aligned) row stride.
//  - 2 barriers/block total (rowsum reduce, O reduce). att written normalized,
//    128 B/row contiguous chunks.
// Outputs: out (8,1024,1024) fp32 ; att (8,16,1024,1064) fp32
// ---------------------------------------------------------------------------

#define B_ 8
#define NQ 1024
#define NK 1024
#define DM 1024
#define H_ 16
#define DK 64
#define NKM 1064   // nk + M
#define NKP 1104   // padded row length for Kh/Vt
#define PSTR 280   // P LDS row stride (bf16); 272 used

typedef __attribute__((ext_vector_type(8))) short bf16x8;
typedef __attribute__((ext_vector_type(4))) float f32x4;
typedef __attribute__((ext_vector_type(4))) short short4v;

static __device__ __forceinline__ short f2bf(float x) {
    __hip_bfloat16 h = __float2bfloat16(x);
    return __builtin_bit_cast(short, h);
}
static __device__ __forceinline__ float bf2f(short s) {
    unsigned int u = ((unsigned int)(unsigned short)s) << 16;
    return __builtin_bit_cast(float, u);
}

static __device__ __forceinline__ bf16x8 pack8(const float* __restrict__ p) {
    float4 f0 = *(const float4*)p;
    float4 f1 = *(const float4*)(p + 4);
    bf16x8 a;
    a[0] = f2bf(f0.x); a[1] = f2bf(f0.y); a[2] = f2bf(f0.z); a[3] = f2bf(f0.w);
    a[4] = f2bf(f1.x); a[5] = f2bf(f1.y); a[6] = f2bf(f1.z); a[7] = f2bf(f1.w);
    return a;
}

// async global->LDS, 16B per lane; LDS dest is wave-uniform base + lane*16
static __device__ __forceinline__ void gload16(const short* g, short* l) {
    __builtin_amdgcn_global_load_lds(
        (__attribute__((address_space(1))) void*)const_cast<short*>(g),
        (__attribute__((address_space(3))) void*)l, 16, 0, 0);
}

// --- mask dtype probe: bool(1B) vs int32(4B) -------------------------------
__global__ void detect_mask_kernel(const unsigned int* __restrict__ m, int n_dwords,
                                   int* __restrict__ flag) {
    __shared__ int any_big;
    if (threadIdx.x == 0) any_big = 0;
    __syncthreads();
    for (int i = threadIdx.x; i < n_dwords; i += blockDim.x)
        if (m[i] > 1u) any_big = 1;
    __syncthreads();
    if (threadIdx.x == 0) *flag = any_big ? 0 : 1;   // 1 => int32, 0 => bytes
}

// --- W (K x N) fp32 -> WT (N x K) bf16 --------------------------------------
__global__ void transpose_w_kernel(const float* __restrict__ W, short* __restrict__ WT) {
    __shared__ float t[32][33];
    int tx = threadIdx.x & 31, ty = threadIdx.x >> 5;
    int k0 = blockIdx.x * 32, n0 = blockIdx.y * 32;
#pragma unroll
    for (int r = 0; r < 4; r++)
        t[ty + 8 * r][tx] = W[(size_t)(k0 + ty + 8 * r) * DM + n0 + tx];
    __syncthreads();
#pragma unroll
    for (int r = 0; r < 4; r++)
        WT[(size_t)(n0 + ty + 8 * r) * DM + k0 + tx] = f2bf(t[tx][ty + 8 * r]);
}

// --- fp32 -> bf16 convert of the 3 input tensors (contiguous dest) ----------
__global__ void convert_bf16_kernel(const float* __restrict__ a, const float* __restrict__ b,
                                    const float* __restrict__ c, short* __restrict__ out) {
    const size_t NT = (size_t)B_ * NQ * DM;          // 8388608 per tensor
    const size_t total = NT * 3;
    size_t i = ((size_t)blockIdx.x * 256 + threadIdx.x) * 8;
    const size_t step = (size_t)gridDim.x * 256 * 8;
    for (; i < total; i += step) {
        const float* src = (i < NT) ? (a + i) : (i < 2 * NT) ? (b + (i - NT)) : (c + (i - 2 * NT));
        *(bf16x8*)(out + i) = pack8(src);
    }
}

// --- memory-slot rows of Kh / Vt (rows 1024..1103; zeros past 1063) --------
__global__ void fill_mem_kernel(const float* __restrict__ m_k, const float* __restrict__ m_v,
                                short* __restrict__ Kh, short* __restrict__ Vt) {
    int blk = blockIdx.x;           // 128 bh * 20 row-groups
    int bh = blk / 20, rb = blk % 20;
    int r = rb * 4 + (threadIdx.x >> 6);    // 0..79
    int d = threadIdx.x & 63;
    int h = bh & 15;
    float kv = 0.f, vv = 0.f;
    if (r < 40) {
        kv = 8.0f * m_k[(size_t)(r * H_ + h) * DK + d];               // sqrt(DK)=8
        vv = 6.324555320336759f * m_v[(size_t)(r * H_ + h) * DK + d]; // sqrt(M)
    }
    int kk = 1024 + r;
    Kh[((size_t)bh * NKP + kk) * 64 + d] = f2bf(kv);
    Vt[((size_t)bh * 64 + d) * NKP + kk] = f2bf(vv);
}

// ---------------------------------------------------------------------------
// m97-style GEMM: C[8192x1024] = A(bf16) @ BT^T + bias (unchanged from r4).
// ---------------------------------------------------------------------------
template <int MODE>
__global__ __launch_bounds__(256) void gemm_tile_kernel(
    const short* __restrict__ Ab, const short* __restrict__ BT,
    const float* __restrict__ bias,
    float* __restrict__ outF, short* __restrict__ outB) {
    __shared__ short As[2][4096];   // [128][32] linear
    __shared__ short Bs[2][4096];

    const int tid = threadIdx.x;
    const int lane = tid & 63;
    const int wid = tid >> 6;
    int swz = (blockIdx.x & 7) * 64 + (blockIdx.x >> 3);
    const int mt = swz >> 3, nt = swz & 7;
    const int brow = mt * 128, bcol = nt * 128;
    const int wr = wid >> 1, wc = wid & 1;
    const int l15 = lane & 15, lg = lane >> 4;

    f32x4 acc[4][4];
#pragma unroll
    for (int m = 0; m < 4; m++)
#pragma unroll
        for (int n = 0; n < 4; n++) acc[m][n] = f32x4{0.f, 0.f, 0.f, 0.f};

    auto stage = [&](int buf, int k0) {
#pragma unroll
        for (int i = 0; i < 2; i++) {
            int c = tid + i * 256;               // 16B chunk id, 0..511
            int row = c >> 2, slot = c & 3;
            int base = (c & ~63) * 8;            // wave-uniform LDS short offset
            gload16(Ab + (size_t)(brow + row) * DM + k0 + slot * 8, &As[buf][base]);
            gload16(BT + (size_t)(bcol + row) * DM + k0 + slot * 8, &Bs[buf][base]);
        }
    };

    stage(0, 0);
    for (int kt = 0; kt < 32; ++kt) {
        __syncthreads();                         // drains gload of buf[kt&1]
        if (kt + 1 < 32) stage((kt + 1) & 1, (kt + 1) * 32);
        const short* Ab_ = As[kt & 1];
        const short* Bb_ = Bs[kt & 1];
        bf16x8 a[4], b[4];
#pragma unroll
        for (int m = 0; m < 4; m++)
            a[m] = *(const bf16x8*)(Ab_ + (wr * 64 + m * 16 + l15) * 32 + lg * 8);
#pragma unroll
        for (int n = 0; n < 4; n++)
            b[n] = *(const bf16x8*)(Bb_ + (wc * 64 + n * 16 + l15) * 32 + lg * 8);
#pragma unroll
        for (int m = 0; m < 4; m++)
#pragma unroll
            for (int n = 0; n < 4; n++)
                acc[m][n] = __builtin_amdgcn_mfma_f32_16x16x32_bf16(a[m], b[n], acc[m][n], 0, 0, 0);
    }

#pragma unroll
    for (int n = 0; n < 4; n++) {
        int col = bcol + wc * 64 + n * 16 + l15;
        float bval = bias[col];
#pragma unroll
        for (int m = 0; m < 4; m++) {
            int row0 = brow + wr * 64 + m * 16 + lg * 4;
            if (MODE == 3) {
#pragma unroll
                for (int r = 0; r < 4; r++)
                    outF[(size_t)(row0 + r) * DM + col] = acc[m][n][r] + bval;
            } else if (MODE == 0) {
                int h = col >> 6, d = col & 63;
#pragma unroll
                for (int r = 0; r < 4; r++) {
                    int row = row0 + r;
                    int b = row >> 10, q = row & 1023;
                    outB[((size_t)(b * H_ + h) * NQ + q) * 64 + d] = f2bf(acc[m][n][r] + bval);
                }
            } else if (MODE == 1) {
                int h = col >> 6, d = col & 63;
#pragma unroll
                for (int r = 0; r < 4; r++) {
                    int row = row0 + r;
                    int b = row >> 10, kk = row & 1023;
                    outB[((size_t)(b * H_ + h) * NKP + kk) * 64 + d] = f2bf(acc[m][n][r] + bval);
                }
            } else {  // MODE 2: Vt[bh][d][kk]
                int h = col >> 6, d = col & 63;
                int b = row0 >> 10, kk0 = row0 & 1023;
                short4v sv;
#pragma unroll
                for (int r = 0; r < 4; r++) sv[r] = f2bf(acc[m][n][r] + bval);
                *(short4v*)(outB + ((size_t)(b * H_ + h) * 64 + d) * NKP + kk0) = sv;
            }
        }
    }
}

// ---------------------------------------------------------------------------
// FUSED attention: QK^T (swapped operands) -> exp -> P in wave-private LDS
// -> rowsum (1 barrier) -> att = P*inv (coalesced) + PV MFMA
// -> cross-wave O reduce (1 barrier) -> Ow.
// Block = 4 waves x same 16 q rows; wave w owns kk in [w*272, w*272+272).
// Per-lane S fragment (mfma(K,Q)): q = lane&15, kk = kt + (lane>>4)*4 + r.
// ---------------------------------------------------------------------------
__global__ __launch_bounds__(256) void attn_fused_kernel(
    const short* __restrict__ Qh, const short* __restrict__ Kh,
    const short* __restrict__ Vt,
    const unsigned char* __restrict__ mb, const int* __restrict__ mi,
    const int* __restrict__ flag,
    float* __restrict__ att, short* __restrict__ Ow) {
    __shared__ short Pl[4][16][PSTR];   // wave-private unnormalized P (bf16)
    __shared__ float redS[4][16];       // per-wave rowsums

    // XCD swizzle: 64 consecutive blocks (one bh) per XCD
    int swz = (blockIdx.x & 7) * 1024 + (blockIdx.x >> 3);
    int bh = swz >> 6;
    int q0 = (swz & 63) * 16;
    int wid = threadIdx.x >> 6;
    int lane = threadIdx.x & 63;
    int l15 = lane & 15, lg = lane >> 4;

    const short* Qb = Qh + (size_t)bh * NQ * 64;
    const short* Kb = Kh + (size_t)bh * NKP * 64;
    const short* Vb = Vt + (size_t)bh * 64 * NKP;
    const int is32 = *flag;

    // Q fragments (B-operand of swapped QK^T): row = q0 + l15
    bf16x8 aq0 = *(const bf16x8*)(Qb + (size_t)(q0 + l15) * 64 + lg * 8);
    bf16x8 aq1 = *(const bf16x8*)(Qb + (size_t)(q0 + l15) * 64 + 32 + lg * 8);

    size_t qrow = (size_t)bh * NQ + q0 + l15;
    const int kkw = wid * 272;                    // wave's kk window

    // ---- phase 1: S -> exp -> P(LDS) + rowsum --------------------------
    float rs = 0.f;
    for (int t = 0; t < 17; ++t) {
        int kt = kkw + t * 16;
        const short* Kr = Kb + (size_t)(kt + l15) * 64;
        bf16x8 k0 = *(const bf16x8*)(Kr + lg * 8);
        bf16x8 k1 = *(const bf16x8*)(Kr + 32 + lg * 8);
        f32x4 s = {0.f, 0.f, 0.f, 0.f};
        s = __builtin_amdgcn_mfma_f32_16x16x32_bf16(k0, aq0, s, 0, 0, 0);
        s = __builtin_amdgcn_mfma_f32_16x16x32_bf16(k1, aq1, s, 0, 0, 0);
        int kkbase = kt + lg * 4;
        unsigned mu = 0;
        if (kkbase < NK) {
            if (is32) {
                int4 mv = *(const int4*)(mi + qrow * NK + kkbase);
                mu = (mv.x ? 1u : 0u) | (mv.y ? 0x100u : 0u) |
                     (mv.z ? 0x10000u : 0u) | (mv.w ? 0x1000000u : 0u);
            } else {
                mu = *(const unsigned*)(mb + qrow * NK + kkbase);
            }
        }
        short4v pv;
#pragma unroll
        for (int r = 0; r < 4; r++) {
            bool dead = (kkbase + r >= NKM) || (((mu >> (8 * r)) & 0xffu) != 0u);
            float e = dead ? 0.f : __expf(s[r] * 0.125f);
            rs += e;
            pv[r] = f2bf(e);
        }
        *(short4v*)(&Pl[wid][l15][t * 16 + lg * 4]) = pv;   // 8B, wave-private
    }
    rs += __shfl_xor(rs, 16);
    rs += __shfl_xor(rs, 32);
    if (lg == 0) redS[wid][l15] = rs;
    __syncthreads();
    float invq = 1.f / (redS[0][l15] + redS[1][l15] + redS[2][l15] + redS[3][l15]);

    // ---- phase 2: att = P*inv + PV ---------------------------------------
    f32x4 po[4];
#pragma unroll
    for (int dt = 0; dt < 4; dt++) po[dt] = f32x4{0.f, 0.f, 0.f, 0.f};

    for (int pp = 0; pp < 9; ++pp) {
        int kks = kkw + pp * 32 + lg * 8;
        bool val = (pp < 8) | (lg < 2);           // pp==8 covers only 16 kk
        bf16x8 a = bf16x8{0, 0, 0, 0, 0, 0, 0, 0};
        if (val) a = *(const bf16x8*)(&Pl[wid][l15][pp * 32 + lg * 8]);
        if (val && kks < NKM) {
            float4 w0, w1;
            w0.x = bf2f(a[0]) * invq; w0.y = bf2f(a[1]) * invq;
            w0.z = bf2f(a[2]) * invq; w0.w = bf2f(a[3]) * invq;
            w1.x = bf2f(a[4]) * invq; w1.y = bf2f(a[5]) * invq;
            w1.z = bf2f(a[6]) * invq; w1.w = bf2f(a[7]) * invq;
            *(float4*)(att + qrow * NKM + kks) = w0;
            *(float4*)(att + qrow * NKM + kks + 4) = w1;
        }
#pragma unroll
        for (int dt = 0; dt < 4; dt++) {
            bf16x8 bv = *(const bf16x8*)(Vb + (size_t)(dt * 16 + l15) * NKP + kkw + pp * 32 + lg * 8);
            po[dt] = __builtin_amdgcn_mfma_f32_16x16x32_bf16(a, bv, po[dt], 0, 0, 0);
        }
    }

    // ---- phase 3: cross-wave O reduce (reuse own P region) ---------------
    float* OredW = (float*)&Pl[wid][0][0];        // [16][68] f32, 4352 B < 8960 B
#pragma unroll
    for (int dt = 0; dt < 4; dt++)
#pragma unroll
        for (int r = 0; r < 4; r++)
            OredW[(lg * 4 + r) * 68 + dt * 16 + l15] = po[dt][r];
    __syncthreads();

    int tq = threadIdx.x >> 4;                    // 0..15
    int d0 = (threadIdx.x & 15) * 4;              // 0..60
    float4 o = {0.f, 0.f, 0.f, 0.f};
#pragma unroll
    for (int w = 0; w < 4; w++) {
        const float* Or = (const float*)&Pl[w][0][0];
        float4 v = *(const float4*)(&Or[tq * 68 + d0]);
        o.x += v.x; o.y += v.y; o.z += v.z; o.w += v.w;
    }
    float invt = 1.f / (redS[0][tq] + redS[1][tq] + redS[2][tq] + redS[3][tq]);
    int b = bh >> 4, h = bh & 15;
    short4v sv;
    sv[0] = f2bf(o.x * invt); sv[1] = f2bf(o.y * invt);
    sv[2] = f2bf(o.z * invt); sv[3] = f2bf(o.w * invt);
    *(short4v*)(Ow + ((size_t)b * NQ + q0 + tq) * DM + h * 64 + d0) = sv;
}

extern "C" void kernel_launch(void* const* d_in, const int* in_sizes, int n_in,
                              void* d_out, int out_size, void* d_ws, size_t ws_size,
                              hipStream_t stream) {
    const float* queries = (const float*)d_in[0];
    const float* keys    = (const float*)d_in[1];
    const float* values  = (const float*)d_in[2];
    const void*  mask    = d_in[3];
    const float* Wq = (const float*)d_in[4];
    const float* bq = (const float*)d_in[5];
    const float* Wk = (const float*)d_in[6];
    const float* bk = (const float*)d_in[7];
    const float* Wv = (const float*)d_in[8];
    const float* bv = (const float*)d_in[9];
    const float* Wo = (const float*)d_in[10];
    const float* bo = (const float*)d_in[11];
    const float* m_k = (const float*)d_in[12];
    const float* m_v = (const float*)d_in[13];

    // workspace layout (~130 MB)
    short* WqT = (short*)d_ws;
    short* WkT = WqT + (size_t)DM * DM;
    short* WvT = WkT + (size_t)DM * DM;
    short* WoT = WvT + (size_t)DM * DM;
    short* Qh  = WoT + (size_t)DM * DM;                 // [128][1024][64]
    short* Kh  = Qh + (size_t)B_ * H_ * NQ * DK;        // [128][1104][64]
    short* Vt  = Kh + (size_t)B_ * H_ * NKP * DK;       // [128][64][1104]
    short* Ow  = Vt + (size_t)B_ * H_ * DK * NKP;       // [8192][1024]
    char*  after = (char*)(Ow + (size_t)B_ * NQ * DM);
    int*   flag = (int*)after;
    short* Qbf  = (short*)(after + 64);                 // bf16 q/k/v inputs
    short* Kbf  = Qbf + (size_t)B_ * NQ * DM;
    short* Vbf  = Kbf + (size_t)B_ * NQ * DM;

    float* outO = (float*)d_out;                         // 8*1024*1024
    float* att  = outO + (size_t)B_ * NQ * DM;           // 8*16*1024*1064

    detect_mask_kernel<<<1, 256, 0, stream>>>((const unsigned int*)mask, 4096, flag);

    dim3 tg(32, 32);
    transpose_w_kernel<<<tg, 256, 0, stream>>>(Wq, WqT);
    transpose_w_kernel<<<tg, 256, 0, stream>>>(Wk, WkT);
    transpose_w_kernel<<<tg, 256, 0, stream>>>(Wv, WvT);
    transpose_w_kernel<<<tg, 256, 0, stream>>>(Wo, WoT);

    convert_bf16_kernel<<<4096, 256, 0, stream>>>(queries, keys, values, Qbf);

    gemm_tile_kernel<0><<<512, 256, 0, stream>>>(Qbf, WqT, bq, nullptr, Qh);
    gemm_tile_kernel<1><<<512, 256, 0, stream>>>(Kbf, WkT, bk, nullptr, Kh);
    gemm_tile_kernel<2><<<512, 256, 0, stream>>>(Vbf, WvT, bv, nullptr, Vt);

    fill_mem_kernel<<<2560, 256, 0, stream>>>(m_k, m_v, Kh, Vt);

    attn_fused_kernel<<<8192, 256, 0, stream>>>(Qh, Kh, Vt,
                                                (const unsigned char*)mask, (const int*)mask,
                                                flag, att, Ow);

    gemm_tile_kernel<3><<<512, 256, 0, stream>>>(Ow, WoT, bo, outO, nullptr);
}